// Round 19
// baseline (49.405 us; speedup 1.0000x reference)
//
#include <hip/hip_runtime.h>

// VQ-VAE quantizer forward. fp8-e4m3 MFMA scores (z*2^4, W*2^14, argmin
// scale-invariant). M=64 rows/block (512 blocks: halves W L2 traffic, 4 MFMA
// per 16-B load) + R16's register diet so it still reaches 3 waves/SIMD:
// acc[2][2] (64 AGPR) + depth-6 ring (24) + PACKED argmin keys (32);
// A frags read per-step from LDS (2x ds_read_b64 per 32 MFMA-cycles).
// mse from the packed best key; quantized gathered from a bf16 W copy.
// z: [32, 256, 32, 32] fp32; weight: [256, 1024] fp32.
// out: quantized [8388608] ++ loss [32768] ++ commitment [32768] ++ embedding [32768]

typedef unsigned short ushort_t;
typedef short          s16x8  __attribute__((ext_vector_type(8)));
typedef float          f32x4  __attribute__((ext_vector_type(4)));
typedef float          f32x16 __attribute__((ext_vector_type(16)));
typedef long           l64x2  __attribute__((ext_vector_type(2)));

__device__ __forceinline__ ushort_t f2bf(float x) {
    unsigned int u = __float_as_uint(x);
    u += 0x7fffu + ((u >> 16) & 1u);          // RNE
    return (ushort_t)(u >> 16);
}
__device__ __forceinline__ float bf2f(ushort_t h) {
    return __uint_as_float(((unsigned int)h) << 16);
}

// ---- prep (R18): 64 blocks = kt(16) x dt6(4); bf16 k-major copy,
// wave-lane-ordered fp8 slab, per-slice wsq partials *2^18 ----
// fp8 slab byte: j*16384 + (k>>8)*4096 + ((k>>6)&3)*1024
//               + (lhi*32 + (k&31))*16 + ((k>>5)&1)*8 + (d&7),  j=d>>4, lhi=(d>>3)&1
__global__ __launch_bounds__(256)
void vq_wprep(const float* __restrict__ w,
              ushort_t* __restrict__ wbf, unsigned char* __restrict__ wf8,
              float* __restrict__ wsqp) {
    __shared__ float tile[64][65];
    __shared__ float psum[64][4];
    const int t   = threadIdx.x;
    const int kt  = blockIdx.x & 15;
    const int dt6 = blockIdx.x >> 4;    // d-slice 0..3 (64 d each)
    const int kk  = t >> 2;             // k-local 0..63
    const int dq  = t & 3;              // d-octet selector within 32-d half
    const int k   = kt * 64 + kk;

    #pragma unroll
    for (int i = 0; i < 16; ++i) {
        const int lin = t + 256 * i;
        const int dd = lin >> 6, k2 = lin & 63;
        tile[dd][k2] = w[(size_t)(dt6 * 64 + dd) * 1024 + kt * 64 + k2];
    }
    __syncthreads();

    float acc = 0.f;
    #pragma unroll
    for (int half = 0; half < 2; ++half) {
        s16x8 hv;
        float vs[8];
        #pragma unroll
        for (int e = 0; e < 8; ++e) {
            const int dd = half * 32 + dq * 8 + e;
            const float v = tile[dd][kk];
            hv[e] = (short)f2bf(v);
            vs[e] = v * 16384.f;              // 2^14 scale for fp8
            acc = fmaf(v, v, acc);
        }
        const int dbase = dt6 * 64 + half * 32 + dq * 8;
        *reinterpret_cast<s16x8*>(&wbf[(size_t)k * 256 + dbase]) = hv;
        unsigned plo = 0, phi = 0;
        plo = __builtin_amdgcn_cvt_pk_fp8_f32(vs[0], vs[1], plo, false);
        plo = __builtin_amdgcn_cvt_pk_fp8_f32(vs[2], vs[3], plo, true);
        phi = __builtin_amdgcn_cvt_pk_fp8_f32(vs[4], vs[5], phi, false);
        phi = __builtin_amdgcn_cvt_pk_fp8_f32(vs[6], vs[7], phi, true);
        const int j   = dbase >> 4;           // 16-d group
        const int lhi = (dbase >> 3) & 1;     // which 8-d half
        const size_t off = (size_t)j * 16384 + (size_t)(k >> 8) * 4096
                         + (size_t)((k >> 6) & 3) * 1024
                         + (size_t)(lhi * 32 + (k & 31)) * 16
                         + (size_t)(((k >> 5) & 1) * 8);
        *reinterpret_cast<unsigned*>(&wf8[off])     = plo;
        *reinterpret_cast<unsigned*>(&wf8[off + 4]) = phi;
    }
    psum[kk][dq] = acc;
    __syncthreads();
    if (t < 64)
        wsqp[dt6 * 1024 + kt * 64 + t] =
            (psum[t][0] + psum[t][1] + psum[t][2] + psum[t][3]) * 262144.f;  // 2^18
}

// ---- main: M=64 rows/block, 512 blocks ----
__global__ __launch_bounds__(256, 3)
void vq_mfma(const float* __restrict__ z,
             const unsigned char* __restrict__ wf8, const ushort_t* __restrict__ wbf,
             const float* __restrict__ wsqp, float* __restrict__ out) {
    __shared__ unsigned char z_f8[64][264];   // [n][d] bytes; 2-way banks
    __shared__ float    psum[16][64];         // z^2 partials [dr][n]
    __shared__ unsigned wred[4][64];          // packed keys per wave
    __shared__ int      kbest[64];

    const int tid  = threadIdx.x;
    const int bid  = blockIdx.x;
    const int b    = bid >> 4;
    const int s0   = (bid & 15) * 64;
    const int lane = tid & 63;
    const int wk   = tid >> 6;          // wave id -> k-quarter of each 256-chunk
    const int l31  = lane & 31;
    const int lhi  = lane >> 5;

    // ---- stage z -> fp8 (x2^4) + z^2 partials (z read ONCE, non-temporal) ----
    {
        const int u  = tid & 15;
        const int sc = u * 4;
        const int dr = tid >> 4;        // 0..15
        float p[4] = {0.f, 0.f, 0.f, 0.f};
        for (int it = 0; it < 16; ++it) {
            const int d = it * 16 + dr;
            const f32x4 v = __builtin_nontemporal_load(
                reinterpret_cast<const f32x4*>(
                    &z[(((size_t)(b * 256 + d)) << 10) + s0 + sc]));
            #pragma unroll
            for (int jj = 0; jj < 4; ++jj) {
                const int j = (jj + u) & 3;           // stagger write banks
                const float zv = v[j];
                const int r8 = __builtin_amdgcn_cvt_pk_fp8_f32(zv * 16.f, 0.f, 0, false);
                z_f8[sc + j][d] = (unsigned char)(r8 & 0xff);
                p[j] = fmaf(zv, zv, p[j]);
            }
        }
        #pragma unroll
        for (int j = 0; j < 4; ++j) psum[dr][sc + j] = p[j];
    }
    __syncthreads();

    // per-lane base into the wave-lane-ordered slab
    const unsigned char* wlane = wf8 + (size_t)wk * 1024 + (size_t)lane * 16;

    unsigned best[2][16];
    #pragma unroll
    for (int m = 0; m < 2; ++m)
        #pragma unroll
        for (int r = 0; r < 16; ++r) best[m][r] = 0xFFFFFFFFu;

    l64x2  bb[6];
    f32x16 acc[2][2];
    for (int c = 0; c < 4; ++c) {           // k-chunks of 256 (ROLLED - register budget)
        const unsigned char* wchunk = wlane + (size_t)c * 4096;
        #pragma unroll
        for (int m = 0; m < 2; ++m)
            #pragma unroll
            for (int nt = 0; nt < 2; ++nt)
                #pragma unroll
                for (int e = 0; e < 16; ++e) acc[m][nt][e] = 0.f;

        // depth-6 preamble: steps j=0..5 (one dwordx4 each: {nt0 8B, nt1 8B})
        #pragma unroll
        for (int p = 0; p < 6; ++p)
            bb[p] = *reinterpret_cast<const l64x2*>(wchunk + (size_t)p * 16384);

        #pragma unroll
        for (int j = 0; j < 16; ++j) {
            const int slot = j % 6;                     // compile-time (j unrolled)
            const long a0 = *reinterpret_cast<const long*>(
                &z_f8[l31][j * 16 + lhi * 8]);          // A frags from LDS (8 B each)
            const long a1 = *reinterpret_cast<const long*>(
                &z_f8[32 + l31][j * 16 + lhi * 8]);
            acc[0][0] = __builtin_amdgcn_mfma_f32_32x32x16_fp8_fp8(a0, bb[slot][0], acc[0][0], 0, 0, 0);
            acc[1][0] = __builtin_amdgcn_mfma_f32_32x32x16_fp8_fp8(a1, bb[slot][0], acc[1][0], 0, 0, 0);
            acc[0][1] = __builtin_amdgcn_mfma_f32_32x32x16_fp8_fp8(a0, bb[slot][1], acc[0][1], 0, 0, 0);
            acc[1][1] = __builtin_amdgcn_mfma_f32_32x32x16_fp8_fp8(a1, bb[slot][1], acc[1][1], 0, 0, 0);
            if (j + 6 < 16)   // prefetch step j+6 into the slot just consumed
                bb[slot] = *reinterpret_cast<const l64x2*>(wchunk + (size_t)(j + 6) * 16384);
        }

        // fold chunk into packed argmin keys (wsq = sum of 4 slice partials)
        #pragma unroll
        for (int nt = 0; nt < 2; ++nt) {
            const int kcol = c * 256 + wk * 64 + nt * 32 + l31;
            const float wq = (wsqp[kcol] + wsqp[1024 + kcol])
                           + (wsqp[2048 + kcol] + wsqp[3072 + kcol]);
            #pragma unroll
            for (int m = 0; m < 2; ++m)
                #pragma unroll
                for (int r = 0; r < 16; ++r) {
                    const float dist = fmaf(-2.f, acc[m][nt][r], wq);   // scaled 2^18
                    const unsigned key = (__float_as_uint(dist + 0x1p21f) & 0xFFFFFC00u)
                                       | (unsigned)kcol;
                    best[m][r] = min(best[m][r], key);
                }
        }
    }

    // ---- in-wave argmin across the 32 k-lanes (packed keys) ----
    #pragma unroll
    for (int off = 1; off < 32; off <<= 1) {
        #pragma unroll
        for (int m = 0; m < 2; ++m)
            #pragma unroll
            for (int r = 0; r < 16; ++r) {
                const unsigned o = (unsigned)__shfl_xor((int)best[m][r], off);
                best[m][r] = min(best[m][r], o);
            }
    }
    if (l31 == 0) {
        #pragma unroll
        for (int m = 0; m < 2; ++m)
            #pragma unroll
            for (int r = 0; r < 16; ++r) {
                const int n = m * 32 + (r & 3) + 8 * (r >> 2) + 4 * lhi;  // row 0..63
                wred[wk][n] = best[m][r];
            }
    }
    __syncthreads();

    // ---- final per-row reduce + loss outputs (mse from packed key) ----
    if (tid < 64) {
        unsigned key = wred[0][tid];
        key = min(key, wred[1][tid]);
        key = min(key, wred[2][tid]);
        key = min(key, wred[3][tid]);
        const int kb = (int)(key & 1023u);
        kbest[tid] = kb;
        const float dist_s = __uint_as_float(key & 0xFFFFFC00u) - 0x1p21f;  // scaled 2^18
        float zs = 0.f;
        #pragma unroll
        for (int r = 0; r < 16; ++r) zs += psum[r][tid];
        const float mse = (zs + dist_s * 0x1p-18f) * (1.f / 256.f);
        const size_t n = (size_t)bid * 64 + tid;
        __builtin_nontemporal_store(1.25f * mse, &out[8388608 + n]);  // loss
        __builtin_nontemporal_store(mse,         &out[8421376 + n]);  // commitment
        __builtin_nontemporal_store(mse,         &out[8454144 + n]);  // embedding
    }
    __syncthreads();

    // ---- quantized epilogue: gather bf16 code row, non-temporal coalesced writes ----
    const int es = tid & 63;
    const int dg = tid >> 6;            // 0..3 -> d-range dg*64..+63
    const int kb = kbest[es];
    #pragma unroll
    for (int si = 0; si < 2; ++si) {
        const size_t base = (size_t)kb * 256 + (dg * 2 + si) * 32;
        #pragma unroll
        for (int part = 0; part < 4; ++part) {
            const s16x8 qh = *reinterpret_cast<const s16x8*>(&wbf[base + part * 8]);
            #pragma unroll
            for (int e = 0; e < 8; ++e) {
                const int d = (dg * 2 + si) * 32 + part * 8 + e;
                __builtin_nontemporal_store(
                    bf2f((ushort_t)qh[e]),
                    &out[(((size_t)(b * 256 + d)) << 10) + s0 + es]);
            }
        }
    }
}

extern "C" void kernel_launch(void* const* d_in, const int* in_sizes, int n_in,
                              void* d_out, int out_size, void* d_ws, size_t ws_size,
                              hipStream_t stream) {
    const float* z = (const float*)d_in[0];
    const float* w = (const float*)d_in[1];
    float* out = (float*)d_out;

    float*         wsqp = (float*)d_ws;                                // 16 KB partials
    unsigned char* wf8  = (unsigned char*)((char*)d_ws + 16384);       // 256 KB wave-lane fp8
    ushort_t*      wbf  = (ushort_t*)((char*)d_ws + 16384 + 262144);   // 512 KB bf16 copy

    vq_wprep<<<64,  256, 0, stream>>>(w, wbf, wf8, wsqp);
    vq_mfma <<<512, 256, 0, stream>>>(z, wf8, wbf, wsqp, out);
}

// Round 20
// 34.281 us; speedup vs baseline: 1.4412x; 1.4412x over previous
//
#include <hip/hip_runtime.h>

// VQ-VAE quantizer forward. fp8-e4m3 MFMA scores (z*2^4, W*2^14, argmin
// scale-invariant). M=32 rows/block, grid 1024. Total register state
// (arch VGPR + AGPR acc) ~128 so HW reaches 3-4 waves/SIMD: acc[2] (32 AGPR),
// a[16] (32), depth-6 B ring (24), PACKED argmin keys (16): key =
// (bits(dist+2^21) & ~1023) | k  ->  single u32 min, tie -> lower k.
// B: one dwordx4/step from wave-lane-ordered slab. c-loop rolled.
// mse from the packed best key; quantized gathered from a bf16 W copy.
// [R20 = R16 restored verbatim: best measured config, 34.3us]
// z: [32, 256, 32, 32] fp32; weight: [256, 1024] fp32.
// out: quantized [8388608] ++ loss [32768] ++ commitment [32768] ++ embedding [32768]

typedef unsigned short ushort_t;
typedef short          s16x8  __attribute__((ext_vector_type(8)));
typedef float          f32x4  __attribute__((ext_vector_type(4)));
typedef float          f32x16 __attribute__((ext_vector_type(16)));
typedef long           l64x2  __attribute__((ext_vector_type(2)));

__device__ __forceinline__ ushort_t f2bf(float x) {
    unsigned int u = __float_as_uint(x);
    u += 0x7fffu + ((u >> 16) & 1u);          // RNE
    return (ushort_t)(u >> 16);
}
__device__ __forceinline__ float bf2f(ushort_t h) {
    return __uint_as_float(((unsigned int)h) << 16);
}

// ---- prep: bf16 k-major copy, wave-lane-ordered fp8 slab, wsq*2^18 ----
// fp8 slab byte: j*16384 + c*4096 + wk*1024 + (lhi*32 + l31)*16 + nt*8 + (d&7)
//   for k = c*256 + wk*64 + nt*32 + l31, j = d>>4, lhi = (d>>3)&1.
__global__ __launch_bounds__(256)
void vq_wprep(const float* __restrict__ w,
              ushort_t* __restrict__ wbf, unsigned char* __restrict__ wf8,
              float* __restrict__ wsq18) {
    __shared__ float tile[64][65];
    __shared__ float psum[64][4];
    const int t  = threadIdx.x;
    const int kt = blockIdx.x;          // 16 blocks, 64 codes each
    const int kk = t >> 2;              // k-local 0..63
    const int dq = t & 3;               // d-octet selector within 32-d half
    const int k  = kt * 64 + kk;
    float acc = 0.f;
    for (int dt6 = 0; dt6 < 4; ++dt6) {
        __syncthreads();
        #pragma unroll
        for (int i = 0; i < 16; ++i) {
            const int lin = t + 256 * i;
            const int dd = lin >> 6, k2 = lin & 63;
            tile[dd][k2] = w[(size_t)(dt6 * 64 + dd) * 1024 + kt * 64 + k2];
        }
        __syncthreads();
        #pragma unroll
        for (int half = 0; half < 2; ++half) {
            s16x8 hv;
            float vs[8];
            #pragma unroll
            for (int e = 0; e < 8; ++e) {
                const int dd = half * 32 + dq * 8 + e;
                const float v = tile[dd][kk];
                hv[e] = (short)f2bf(v);
                vs[e] = v * 16384.f;              // 2^14 scale for fp8
                acc = fmaf(v, v, acc);
            }
            const int dbase = dt6 * 64 + half * 32 + dq * 8;
            *reinterpret_cast<s16x8*>(&wbf[(size_t)k * 256 + dbase]) = hv;
            unsigned plo = 0, phi = 0;
            plo = __builtin_amdgcn_cvt_pk_fp8_f32(vs[0], vs[1], plo, false);
            plo = __builtin_amdgcn_cvt_pk_fp8_f32(vs[2], vs[3], plo, true);
            phi = __builtin_amdgcn_cvt_pk_fp8_f32(vs[4], vs[5], phi, false);
            phi = __builtin_amdgcn_cvt_pk_fp8_f32(vs[6], vs[7], phi, true);
            const int j   = dbase >> 4;           // 16-d group
            const int lhi = (dbase >> 3) & 1;     // which 8-d half
            const size_t off = (size_t)j * 16384 + (size_t)(k >> 8) * 4096
                             + (size_t)((k >> 6) & 3) * 1024
                             + (size_t)(lhi * 32 + (k & 31)) * 16
                             + (size_t)(((k >> 5) & 1) * 8);
            *reinterpret_cast<unsigned*>(&wf8[off])     = plo;
            *reinterpret_cast<unsigned*>(&wf8[off + 4]) = phi;
        }
    }
    psum[kk][dq] = acc;
    __syncthreads();
    if (t < 64)
        wsq18[kt * 64 + t] = (psum[t][0] + psum[t][1] + psum[t][2] + psum[t][3])
                             * 262144.f;   // 2^18
}

// ---- main: M=32 rows/block, 1024 blocks ----
__global__ __launch_bounds__(256, 3)
void vq_mfma(const float* __restrict__ z,
             const unsigned char* __restrict__ wf8, const ushort_t* __restrict__ wbf,
             const float* __restrict__ wsq18, float* __restrict__ out) {
    __shared__ unsigned char z_f8[32][264];   // [n][d] bytes; 2-way banks
    __shared__ float    psum[32][32];         // z^2 partials [dr][n]
    __shared__ unsigned wred[4][32];          // packed keys per wave
    __shared__ int      kbest[32];

    const int tid  = threadIdx.x;
    const int bid  = blockIdx.x;
    const int b    = bid >> 5;          // 32 blocks per 1024-elem HW plane
    const int s0   = (bid & 31) * 32;
    const int lane = tid & 63;
    const int wk   = tid >> 6;          // wave id -> k-quarter of each 256-chunk
    const int l31  = lane & 31;
    const int lhi  = lane >> 5;

    // ---- stage z -> fp8 (x2^4) + z^2 partials (z read ONCE, non-temporal) ----
    {
        const int u  = tid & 7;
        const int sc = u * 4;
        const int dr = tid >> 3;        // 0..31
        float p[4] = {0.f, 0.f, 0.f, 0.f};
        #pragma unroll
        for (int it = 0; it < 8; ++it) {
            const int d = it * 32 + dr;
            const f32x4 v = __builtin_nontemporal_load(
                reinterpret_cast<const f32x4*>(
                    &z[(((size_t)(b * 256 + d)) << 10) + s0 + sc]));
            #pragma unroll
            for (int jj = 0; jj < 4; ++jj) {
                const int j = (jj + u) & 3;           // stagger write banks
                const float zv = v[j];
                const int r8 = __builtin_amdgcn_cvt_pk_fp8_f32(zv * 16.f, 0.f, 0, false);
                z_f8[sc + j][d] = (unsigned char)(r8 & 0xff);
                p[j] = fmaf(zv, zv, p[j]);
            }
        }
        #pragma unroll
        for (int j = 0; j < 4; ++j) psum[dr][sc + j] = p[j];
    }
    __syncthreads();

    // ---- A fragments -> registers (row = l31, d = j*16 + lhi*8 + e) ----
    long a[16];
    #pragma unroll
    for (int j = 0; j < 16; ++j)
        a[j] = *reinterpret_cast<const long*>(&z_f8[l31][j * 16 + lhi * 8]);

    // per-lane base into the wave-lane-ordered slab
    const unsigned char* wlane = wf8 + (size_t)wk * 1024 + (size_t)lane * 16;

    unsigned best[16];
    #pragma unroll
    for (int r = 0; r < 16; ++r) best[r] = 0xFFFFFFFFu;

    l64x2  bb[6];
    f32x16 acc[2];
    for (int c = 0; c < 4; ++c) {           // k-chunks of 256 (ROLLED - register budget)
        const unsigned char* wchunk = wlane + (size_t)c * 4096;
        #pragma unroll
        for (int nt = 0; nt < 2; ++nt)
            #pragma unroll
            for (int e = 0; e < 16; ++e) acc[nt][e] = 0.f;

        // depth-6 preamble: steps j=0..5 (one dwordx4 each: {nt0 8B, nt1 8B})
        #pragma unroll
        for (int p = 0; p < 6; ++p)
            bb[p] = *reinterpret_cast<const l64x2*>(wchunk + (size_t)p * 16384);

        #pragma unroll
        for (int j = 0; j < 16; ++j) {
            const int slot = j % 6;                     // compile-time (j unrolled)
            acc[0] = __builtin_amdgcn_mfma_f32_32x32x16_fp8_fp8(a[j], bb[slot][0], acc[0], 0, 0, 0);
            acc[1] = __builtin_amdgcn_mfma_f32_32x32x16_fp8_fp8(a[j], bb[slot][1], acc[1], 0, 0, 0);
            if (j + 6 < 16)   // prefetch step j+6 into the slot just consumed
                bb[slot] = *reinterpret_cast<const l64x2*>(wchunk + (size_t)(j + 6) * 16384);
        }

        // fold chunk into packed argmin keys
        #pragma unroll
        for (int nt = 0; nt < 2; ++nt) {
            const int kcol = c * 256 + wk * 64 + nt * 32 + l31;
            const float wq = wsq18[kcol];
            #pragma unroll
            for (int r = 0; r < 16; ++r) {
                const float dist = fmaf(-2.f, acc[nt][r], wq);       // scaled 2^18
                const unsigned key = (__float_as_uint(dist + 0x1p21f) & 0xFFFFFC00u)
                                   | (unsigned)kcol;
                best[r] = min(best[r], key);
            }
        }
    }

    // ---- in-wave argmin across the 32 k-lanes (packed keys) ----
    #pragma unroll
    for (int off = 1; off < 32; off <<= 1) {
        #pragma unroll
        for (int r = 0; r < 16; ++r) {
            const unsigned o = (unsigned)__shfl_xor((int)best[r], off);
            best[r] = min(best[r], o);
        }
    }
    if (l31 == 0) {
        #pragma unroll
        for (int r = 0; r < 16; ++r) {
            const int n = (r & 3) + 8 * (r >> 2) + 4 * lhi;   // output row 0..31
            wred[wk][n] = best[r];
        }
    }
    __syncthreads();

    // ---- final per-row reduce + loss outputs (mse from packed key) ----
    if (tid < 32) {
        unsigned key = wred[0][tid];
        key = min(key, wred[1][tid]);
        key = min(key, wred[2][tid]);
        key = min(key, wred[3][tid]);
        const int kb = (int)(key & 1023u);
        kbest[tid] = kb;
        const float dist_s = __uint_as_float(key & 0xFFFFFC00u) - 0x1p21f;  // scaled 2^18
        float zs = 0.f;
        #pragma unroll
        for (int r = 0; r < 32; ++r) zs += psum[r][tid];
        const float mse = (zs + dist_s * 0x1p-18f) * (1.f / 256.f);
        const size_t n = (size_t)bid * 32 + tid;
        __builtin_nontemporal_store(1.25f * mse, &out[8388608 + n]);  // loss
        __builtin_nontemporal_store(mse,         &out[8421376 + n]);  // commitment
        __builtin_nontemporal_store(mse,         &out[8454144 + n]);  // embedding
    }
    __syncthreads();

    // ---- quantized epilogue: gather bf16 code row, non-temporal coalesced writes ----
    const int es = tid & 31;            // row (s-offset)
    const int dg = tid >> 5;            // 0..7 -> 32 d each
    const int kb = kbest[es];
    const size_t base = (size_t)kb * 256 + dg * 32;
    #pragma unroll
    for (int part = 0; part < 4; ++part) {
        const s16x8 qh = *reinterpret_cast<const s16x8*>(&wbf[base + part * 8]);
        #pragma unroll
        for (int e = 0; e < 8; ++e) {
            const int d = dg * 32 + part * 8 + e;
            __builtin_nontemporal_store(
                bf2f((ushort_t)qh[e]),
                &out[(((size_t)(b * 256 + d)) << 10) + s0 + es]);
        }
    }
}

extern "C" void kernel_launch(void* const* d_in, const int* in_sizes, int n_in,
                              void* d_out, int out_size, void* d_ws, size_t ws_size,
                              hipStream_t stream) {
    const float* z = (const float*)d_in[0];
    const float* w = (const float*)d_in[1];
    float* out = (float*)d_out;

    float*         wsq18 = (float*)d_ws;                               // 4 KB
    unsigned char* wf8   = (unsigned char*)((char*)d_ws + 4096);       // 256 KB wave-lane fp8
    ushort_t*      wbf   = (ushort_t*)((char*)d_ws + 4096 + 262144);   // 512 KB bf16 copy

    vq_wprep<<<16,   256, 0, stream>>>(w, wbf, wf8, wsq18);
    vq_mfma <<<1024, 256, 0, stream>>>(z, wf8, wbf, wsq18, out);
}